// Round 1
// baseline (588.824 us; speedup 1.0000x reference)
//
#include <hip/hip_runtime.h>
#include <hip/hip_bf16.h>

#define S_LEN 2048
#define DH 64
#define NBATCH 4
#define LOG2E 1.44269504088896f
#define NEG_BIG -1e10f

typedef __attribute__((ext_vector_type(8))) short short8;
typedef __attribute__((ext_vector_type(4))) float floatx4;

__device__ inline float fast_exp2(float x) {
#if __has_builtin(__builtin_amdgcn_exp2f)
  return __builtin_amdgcn_exp2f(x);
#else
  return exp2f(x);
#endif
}

// fp32 -> bf16 round-to-nearest-even (finite inputs only)
__device__ inline short f2bf(float x) {
  union { float f; unsigned u; } v; v.f = x;
  unsigned r = v.u + 0x7fffu + ((v.u >> 16) & 1u);
  return (short)(r >> 16);
}

__device__ inline short8 pack8(float4 a, float4 b) {
  short8 r;
  r[0] = f2bf(a.x); r[1] = f2bf(a.y); r[2] = f2bf(a.z); r[3] = f2bf(a.w);
  r[4] = f2bf(b.x); r[5] = f2bf(b.y); r[6] = f2bf(b.z); r[7] = f2bf(b.w);
  return r;
}

// Flash attention fwd. Bq=128 (4 waves x 32 rows), Bk=64.
// grid = (16 q-tiles, 64 bh), block = 256.
__global__ __launch_bounds__(256, 2) void flash_fwd(
    const float* __restrict__ Qg, const float* __restrict__ Kg,
    const float* __restrict__ Vg, const int* __restrict__ maskg,
    float* __restrict__ Og)
{
  const int qt  = blockIdx.x;
  const int bh  = blockIdx.y;
  const int b   = bh & (NBATCH - 1);   // h-major layout: b = bh % bs
  const int tid = (int)threadIdx.x;
  const int w = tid >> 6, lane = tid & 63;
  const int g = lane >> 4, c = lane & 15;

  __shared__ __align__(16) short Ks[64 * 72];      // [key][d], bf16, pad 8
  __shared__ __align__(16) short Vt[64 * 72];      // [d][key], bf16 (transposed)
  __shared__ __align__(16) short Ps[4][32 * 72];   // per-wave P [qlocal][key]

  // Q fragments: A[m=c][k = ks*32 + g*8 + j]
  short8 qf[2][2];
#pragma unroll
  for (int s2 = 0; s2 < 2; ++s2) {
    const float* qp = Qg + ((size_t)bh * S_LEN + qt * 128 + w * 32 + s2 * 16 + c) * DH + g * 8;
#pragma unroll
    for (int ks = 0; ks < 2; ++ks) {
      float4 a  = *(const float4*)(qp + ks * 32);
      float4 bq = *(const float4*)(qp + ks * 32 + 4);
      qf[s2][ks] = pack8(a, bq);
    }
  }

  floatx4 acc[2][4];
  float mrow[2][4], lrow[2][4];
#pragma unroll
  for (int s2 = 0; s2 < 2; ++s2) {
#pragma unroll
    for (int i = 0; i < 4; ++i) acc[s2][i] = (floatx4){0.f, 0.f, 0.f, 0.f};
#pragma unroll
    for (int r = 0; r < 4; ++r) { mrow[s2][r] = -3.4e38f; lrow[s2][r] = 0.f; }
  }

  const int rstage = tid >> 2;         // key row 0..63
  const int dstage = (tid & 3) * 16;   // d offset
  const int ktmax = 2 * qt + 1;

  for (int kt = 0; kt <= ktmax; ++kt) {
    __syncthreads();
    { // stage K (row-major) and V (transposed) as bf16
      const size_t rowbase = ((size_t)bh * S_LEN + kt * 64 + rstage) * DH + dstage;
      const float* kp = Kg + rowbase;
      const float* vp = Vg + rowbase;
      float4 k0 = *(const float4*)kp;       float4 k1 = *(const float4*)(kp + 4);
      float4 k2 = *(const float4*)(kp + 8); float4 k3 = *(const float4*)(kp + 12);
      *(short8*)&Ks[rstage * 72 + dstage]     = pack8(k0, k1);
      *(short8*)&Ks[rstage * 72 + dstage + 8] = pack8(k2, k3);
      float4 v0 = *(const float4*)vp;       float4 v1 = *(const float4*)(vp + 4);
      float4 v2 = *(const float4*)(vp + 8); float4 v3 = *(const float4*)(vp + 12);
      float vv[16] = {v0.x, v0.y, v0.z, v0.w, v1.x, v1.y, v1.z, v1.w,
                      v2.x, v2.y, v2.z, v2.w, v3.x, v3.y, v3.z, v3.w};
#pragma unroll
      for (int i = 0; i < 16; ++i) Vt[(dstage + i) * 72 + rstage] = f2bf(vv[i]);
    }
    __syncthreads();

    // padding mask for this K tile (fp32 additive, preserves -1e10 collapse)
    float padv[4];
#pragma unroll
    for (int nt = 0; nt < 4; ++nt)
      padv[nt] = (maskg[b * S_LEN + kt * 64 + nt * 16 + c] != 0) ? 0.f : NEG_BIG;

    // K fragments: B^T[n=key][k-contig]
    short8 kf[2][4];
#pragma unroll
    for (int ks = 0; ks < 2; ++ks)
#pragma unroll
      for (int nt = 0; nt < 4; ++nt)
        kf[ks][nt] = *(const short8*)&Ks[(nt * 16 + c) * 72 + ks * 32 + g * 8];

    bool act[2];
#pragma unroll
    for (int s2 = 0; s2 < 2; ++s2)
      act[s2] = (kt * 64) <= (qt * 128 + w * 32 + s2 * 16 + 15);

#pragma unroll
    for (int s2 = 0; s2 < 2; ++s2) {
      if (!act[s2]) continue;
      floatx4 sv[4];
#pragma unroll
      for (int nt = 0; nt < 4; ++nt) {
        floatx4 cc = (floatx4){0.f, 0.f, 0.f, 0.f};
        cc = __builtin_amdgcn_mfma_f32_16x16x32_bf16(qf[s2][0], kf[0][nt], cc, 0, 0, 0);
        cc = __builtin_amdgcn_mfma_f32_16x16x32_bf16(qf[s2][1], kf[1][nt], cc, 0, 0, 0);
        sv[nt] = cc;
      }
      const int qrow0 = qt * 128 + w * 32 + s2 * 16 + g * 4;  // + r
#pragma unroll
      for (int nt = 0; nt < 4; ++nt) {
        const int key = kt * 64 + nt * 16 + c;
#pragma unroll
        for (int r = 0; r < 4; ++r) {
          float s = sv[nt][r] * 0.125f + padv[nt];
          if (key > qrow0 + r) s = -3.0e38f;   // causal: exp -> exactly 0
          sv[nt][r] = s;
        }
      }
#pragma unroll
      for (int r = 0; r < 4; ++r) {
        float mx = fmaxf(fmaxf(sv[0][r], sv[1][r]), fmaxf(sv[2][r], sv[3][r]));
        mx = fmaxf(mx, __shfl_xor(mx, 1));
        mx = fmaxf(mx, __shfl_xor(mx, 2));
        mx = fmaxf(mx, __shfl_xor(mx, 4));
        mx = fmaxf(mx, __shfl_xor(mx, 8));
        const float mold = mrow[s2][r];
        const float mnew = fmaxf(mold, mx);
        const float corr = fast_exp2((mold - mnew) * LOG2E);
        float ps = 0.f;
#pragma unroll
        for (int nt = 0; nt < 4; ++nt) {
          float p = fast_exp2((sv[nt][r] - mnew) * LOG2E);
          sv[nt][r] = p;
          ps += p;
        }
        ps += __shfl_xor(ps, 1);
        ps += __shfl_xor(ps, 2);
        ps += __shfl_xor(ps, 4);
        ps += __shfl_xor(ps, 8);
        lrow[s2][r] = lrow[s2][r] * corr + ps;
        mrow[s2][r] = mnew;
#pragma unroll
        for (int dt = 0; dt < 4; ++dt) acc[s2][dt][r] *= corr;
      }
      // P (C-layout) -> LDS [qlocal][key] for A-frag re-read
#pragma unroll
      for (int nt = 0; nt < 4; ++nt)
#pragma unroll
        for (int r = 0; r < 4; ++r)
          Ps[w][(s2 * 16 + g * 4 + r) * 72 + nt * 16 + c] = f2bf(sv[nt][r]);
    }

    // PV: O += P*V, V frags shared across both row-subtiles
#pragma unroll
    for (int ks = 0; ks < 2; ++ks) {
      short8 pf0 = {}, pf1 = {};
      if (act[0]) pf0 = *(const short8*)&Ps[w][c * 72 + ks * 32 + g * 8];
      if (act[1]) pf1 = *(const short8*)&Ps[w][(16 + c) * 72 + ks * 32 + g * 8];
#pragma unroll
      for (int dt = 0; dt < 4; ++dt) {
        short8 vf = *(const short8*)&Vt[(dt * 16 + c) * 72 + ks * 32 + g * 8];
        if (act[0]) acc[0][dt] = __builtin_amdgcn_mfma_f32_16x16x32_bf16(pf0, vf, acc[0][dt], 0, 0, 0);
        if (act[1]) acc[1][dt] = __builtin_amdgcn_mfma_f32_16x16x32_bf16(pf1, vf, acc[1][dt], 0, 0, 0);
      }
    }
  }

  // epilogue: O = acc / l
#pragma unroll
  for (int s2 = 0; s2 < 2; ++s2) {
    float rl[4];
#pragma unroll
    for (int r = 0; r < 4; ++r) rl[r] = 1.f / lrow[s2][r];
    const size_t obase = ((size_t)bh * S_LEN + qt * 128 + w * 32 + s2 * 16 + g * 4) * DH + c;
#pragma unroll
    for (int dt = 0; dt < 4; ++dt)
#pragma unroll
      for (int r = 0; r < 4; ++r)
        Og[obase + (size_t)r * DH + dt * 16] = acc[s2][dt][r] * rl[r];
  }
}

// Rows q < f_b (f_b = first unpadded key of batch b) collapse in the fp32
// reference to a UNIFORM average over {k<=q} U {k>q, mask=1}. Overwrite them.
__global__ void fixup(const float* __restrict__ Vg, const int* __restrict__ maskg,
                      float* __restrict__ Og)
{
  const int bh = blockIdx.x;
  const int b  = bh & (NBATCH - 1);
  const int tid = (int)threadIdx.x;
  __shared__ int sFirst;
  __shared__ float sRed[4][64];
  __shared__ int sCnt[4];
  if (tid == 0) sFirst = S_LEN;
  __syncthreads();
  int loc = S_LEN;
  for (int k = tid; k < S_LEN; k += 256) {
    if (maskg[b * S_LEN + k] != 0) { loc = k; break; }
  }
  atomicMin(&sFirst, loc);
  __syncthreads();
  const int f = sFirst;
  if (f == 0) return;

  const int d = tid & 63, kg = tid >> 6;
  float a = 0.f; int cnt = 0;
  for (int k = kg; k < S_LEN; k += 4) {
    if (maskg[b * S_LEN + k] != 0) { a += Vg[((size_t)bh * S_LEN + k) * DH + d]; cnt++; }
  }
  sRed[kg][d] = a;
  if (d == 0) sCnt[kg] = cnt;
  __syncthreads();
  if (tid < 64) {
    const float ms = sRed[0][tid] + sRed[1][tid] + sRed[2][tid] + sRed[3][tid];
    const int n = sCnt[0] + sCnt[1] + sCnt[2] + sCnt[3];
    float pre = 0.f;
    for (int q = 0; q < f; ++q) {
      pre += Vg[((size_t)bh * S_LEN + q) * DH + tid];
      Og[((size_t)bh * S_LEN + q) * DH + tid] = (pre + ms) / (float)(q + 1 + n);
    }
  }
}

extern "C" void kernel_launch(void* const* d_in, const int* in_sizes, int n_in,
                              void* d_out, int out_size, void* d_ws, size_t ws_size,
                              hipStream_t stream) {
  const float* Q = (const float*)d_in[0];
  const float* K = (const float*)d_in[1];
  const float* V = (const float*)d_in[2];
  const int* mask = (const int*)d_in[3];
  float* O = (float*)d_out;
  dim3 grid(16, 64);
  flash_fwd<<<grid, dim3(256), 0, stream>>>(Q, K, V, mask, O);
  fixup<<<dim3(64), dim3(256), 0, stream>>>(V, mask, O);
}

// Round 3
// 262.562 us; speedup vs baseline: 2.2426x; 2.2426x over previous
//
#include <hip/hip_runtime.h>
#include <hip/hip_bf16.h>

#define S_LEN 2048
#define DH 64
#define NBATCH 4
#define LOG2E 1.44269504088896f
#define SCL2E 0.18033688011112042f      /* 0.125 * log2(e) */
#define PADC  (-1.44269504088896e10f)   /* -1e10 * log2(e): exp2 -> exactly 0 */
#define NEG_BIG -1e10f
#define NEG_CAUSAL -3.0e38f

typedef __attribute__((ext_vector_type(8))) short short8;
typedef __attribute__((ext_vector_type(4))) float floatx4;

__device__ inline float fast_exp2(float x) {
#if __has_builtin(__builtin_amdgcn_exp2f)
  return __builtin_amdgcn_exp2f(x);
#else
  return exp2f(x);
#endif
}

// fp32 -> bf16 round-to-nearest-even (finite inputs only)
__device__ inline short f2bf(float x) {
  union { float f; unsigned u; } v; v.f = x;
  unsigned r = v.u + 0x7fffu + ((v.u >> 16) & 1u);
  return (short)(r >> 16);
}

__device__ inline short8 pack8(float4 a, float4 b) {
  short8 r;
  r[0] = f2bf(a.x); r[1] = f2bf(a.y); r[2] = f2bf(a.z); r[3] = f2bf(a.w);
  r[4] = f2bf(b.x); r[5] = f2bf(b.y); r[6] = f2bf(b.z); r[7] = f2bf(b.w);
  return r;
}

#define MFMA32(a, b, c) __builtin_amdgcn_mfma_f32_16x16x32_bf16(a, b, c, 0, 0, 0)

// ---------------- pre-pass: K -> fragment-linear bf16 tiles -----------------
// chunk idx = ((bh*32+kt)*8 + ks*4+nt)*64 + lane; lane(c,g) holds
// K[bh][kt*64+nt*16+c][ks*32+g*8 .. +7]  (A/B frag for 16x16x32, 16B)
__global__ void prep_k(const float* __restrict__ Kg, short8* __restrict__ Kf) {
  const int idx = blockIdx.x * 256 + threadIdx.x;   // 0 .. 1048575
  const int lane = idx & 63;
  const int t = idx >> 6;
  const int nt = t & 3, ks = (t >> 2) & 1;
  const int kt = (t >> 3) & 31;
  const int bh = t >> 8;
  const int c = lane & 15, g = lane >> 4;
  const float* src = Kg + ((size_t)bh * S_LEN + kt * 64 + nt * 16 + c) * DH + ks * 32 + g * 8;
  float4 a = *(const float4*)src;
  float4 b = *(const float4*)(src + 4);
  Kf[idx] = pack8(a, b);
}

// ---------------- pre-pass: V -> permuted-k B-fragments (bf16) --------------
// chunk idx = ((bh*32+kt)*8 + nt2*4+dt)*64 + lane; slot (g,j) maps to key
// kappa = kt*64 + nt2*32 + (j>=4)*16 + g*4 + (j&3); lane(c,g) slot j holds
// V[kappa][dt*16+c]. This matches the A-frag built from the S^T C-layout:
// P tile (2*nt2) occupies slots 0..3 (r=j), tile (2*nt2+1) slots 4..7.
__global__ void prep_v(const float* __restrict__ Vg, short8* __restrict__ Vf) {
  const int idx = blockIdx.x * 256 + threadIdx.x;   // 0 .. 1048575
  const int lane = idx & 63;
  const int t = idx >> 6;
  const int dt = t & 3, nt2 = (t >> 2) & 1;
  const int kt = (t >> 3) & 31;
  const int bh = t >> 8;
  const int c = lane & 15, g = lane >> 4;
  const int key0 = kt * 64 + nt2 * 32 + g * 4;
  const float* src = Vg + ((size_t)bh * S_LEN + key0) * DH + dt * 16 + c;
  short8 r;
#pragma unroll
  for (int j = 0; j < 4; ++j) r[j] = f2bf(src[(size_t)j * DH]);
#pragma unroll
  for (int j = 0; j < 4; ++j) r[4 + j] = f2bf(src[(size_t)(16 + j) * DH]);
  Vf[idx] = r;
}

// ---------------- main flash kernel: no LDS, no barriers --------------------
// grid = (64 bh, 16 qt'), qt = 15 - qt' (longest blocks dispatch first)
__global__ __launch_bounds__(256, 2) void flash_fwd2(
    const float* __restrict__ Qg, const int* __restrict__ maskg,
    const short8* __restrict__ KfB, const short8* __restrict__ VfB,
    float* __restrict__ Og)
{
  const int bh = blockIdx.x;
  const int qt = 15 - (int)blockIdx.y;
  const int b  = bh & (NBATCH - 1);
  const int tid = (int)threadIdx.x;
  const int w = tid >> 6, lane = tid & 63;
  const int c = lane & 15, g = lane >> 4;
  const int qbase = qt * 128 + w * 32;

  // Q as B-fragments: lane(c,g) holds Q[q=qbase+s2*16+c][d=ks*32+g*8..+7]
  short8 qf[2][2];
#pragma unroll
  for (int s2 = 0; s2 < 2; ++s2) {
    const float* qp = Qg + ((size_t)bh * S_LEN + qbase + s2 * 16 + c) * DH + g * 8;
#pragma unroll
    for (int ks = 0; ks < 2; ++ks) {
      float4 a  = *(const float4*)(qp + ks * 32);
      float4 b4 = *(const float4*)(qp + ks * 32 + 4);
      qf[s2][ks] = pack8(a, b4);
    }
  }

  floatx4 acc[2][4];
  float lp[2] = {0.f, 0.f};
#pragma unroll
  for (int s2 = 0; s2 < 2; ++s2)
#pragma unroll
    for (int dt = 0; dt < 4; ++dt) acc[s2][dt] = (floatx4){0.f, 0.f, 0.f, 0.f};

  const int ktmax = 2 * qt + 1;
  for (int kt = 0; kt <= ktmax; ++kt) {
    // K fragments (16B coalesced, L1/L2/L3-cached, shared by all 4 waves)
    const short8* kfp = KfB + ((size_t)(bh * 32 + kt) * 8) * 64 + lane;
    short8 kf[2][4];
#pragma unroll
    for (int ks = 0; ks < 2; ++ks)
#pragma unroll
      for (int nt = 0; nt < 4; ++nt) kf[ks][nt] = kfp[(ks * 4 + nt) * 64];

    // V fragments (16B coalesced, pre-permuted)
    const short8* vfp = VfB + ((size_t)(bh * 32 + kt) * 8) * 64 + lane;
    short8 vf[2][4];
#pragma unroll
    for (int nt2 = 0; nt2 < 2; ++nt2)
#pragma unroll
      for (int dt = 0; dt < 4; ++dt) vf[nt2][dt] = vfp[(nt2 * 4 + dt) * 64];

    // padding add (pre-multiplied by log2e), per key = kt*64+nt*16+g*4+r
    floatx4 padv[4];
#pragma unroll
    for (int nt = 0; nt < 4; ++nt) {
      int4 mv = *(const int4*)&maskg[b * S_LEN + kt * 64 + nt * 16 + g * 4];
      padv[nt][0] = mv.x ? 0.f : PADC;
      padv[nt][1] = mv.y ? 0.f : PADC;
      padv[nt][2] = mv.z ? 0.f : PADC;
      padv[nt][3] = mv.w ? 0.f : PADC;
    }

#pragma unroll
    for (int s2 = 0; s2 < 2; ++s2) {
      if (kt * 64 > qbase + s2 * 16 + 15) continue;   // fully above diagonal
      // S^T = K . Q^T : lane(c,g) reg r holds S[key=kt*64+nt*16+g*4+r][q=c]
      floatx4 st[4];
#pragma unroll
      for (int nt = 0; nt < 4; ++nt) {
        floatx4 cc = (floatx4){0.f, 0.f, 0.f, 0.f};
        cc = MFMA32(kf[0][nt], qf[s2][0], cc);
        cc = MFMA32(kf[1][nt], qf[s2][1], cc);
        st[nt] = cc;
      }
      const int q = qbase + s2 * 16 + c;
      const bool causal = (kt * 64 + 63) > (qbase + s2 * 16);
      short8 pP[2];   // A-frags: tile (2*nt2) -> slots 0..3, tile (2*nt2+1) -> 4..7
#pragma unroll
      for (int nt = 0; nt < 4; ++nt) {
#pragma unroll
        for (int r = 0; r < 4; ++r) {
          float arg = fmaf(st[nt][r], SCL2E, padv[nt][r]);
          if (causal) {
            const int key = kt * 64 + nt * 16 + g * 4 + r;
            arg = (key > q) ? NEG_CAUSAL : arg;
          }
          float p = fast_exp2(arg);     // fixed-max softmax: m == 0
          lp[s2] += p;
          pP[nt >> 1][(nt & 1) * 4 + r] = f2bf(p);
        }
      }
      // PV with permuted-k 16x16x32 MFMA: P never leaves registers
#pragma unroll
      for (int nt2 = 0; nt2 < 2; ++nt2)
#pragma unroll
        for (int dt = 0; dt < 4; ++dt)
          acc[s2][dt] = MFMA32(pP[nt2], vf[nt2][dt], acc[s2][dt]);
    }
  }

  // epilogue: reduce l across lanes with same q (xor 16,32), broadcast to rows
#pragma unroll
  for (int s2 = 0; s2 < 2; ++s2) {
    float l = lp[s2];
    l += __shfl_xor(l, 16);
    l += __shfl_xor(l, 32);
    const float linv = 1.f / l;        // inf for all-masked-prefix rows (fixup overwrites)
    float rr[4];
#pragma unroll
    for (int r = 0; r < 4; ++r) rr[r] = __shfl(linv, g * 4 + r);
#pragma unroll
    for (int dt = 0; dt < 4; ++dt)
#pragma unroll
      for (int r = 0; r < 4; ++r)
        Og[((size_t)bh * S_LEN + qbase + s2 * 16 + g * 4 + r) * DH + dt * 16 + c] =
            acc[s2][dt][r] * rr[r];
  }
}

// ---------------- fallback (ws too small): round-1 kernel ------------------
__global__ __launch_bounds__(256, 2) void flash_fwd_lds(
    const float* __restrict__ Qg, const float* __restrict__ Kg,
    const float* __restrict__ Vg, const int* __restrict__ maskg,
    float* __restrict__ Og)
{
  const int qt  = blockIdx.x;
  const int bh  = blockIdx.y;
  const int b   = bh & (NBATCH - 1);
  const int tid = (int)threadIdx.x;
  const int w = tid >> 6, lane = tid & 63;
  const int g = lane >> 4, c = lane & 15;

  __shared__ __align__(16) short Ks[64 * 72];
  __shared__ __align__(16) short Vt[64 * 72];
  __shared__ __align__(16) short Ps[4][32 * 72];

  short8 qf[2][2];
#pragma unroll
  for (int s2 = 0; s2 < 2; ++s2) {
    const float* qp = Qg + ((size_t)bh * S_LEN + qt * 128 + w * 32 + s2 * 16 + c) * DH + g * 8;
#pragma unroll
    for (int ks = 0; ks < 2; ++ks) {
      float4 a  = *(const float4*)(qp + ks * 32);
      float4 bq = *(const float4*)(qp + ks * 32 + 4);
      qf[s2][ks] = pack8(a, bq);
    }
  }

  floatx4 acc[2][4];
  float mrow[2][4], lrow[2][4];
#pragma unroll
  for (int s2 = 0; s2 < 2; ++s2) {
#pragma unroll
    for (int i = 0; i < 4; ++i) acc[s2][i] = (floatx4){0.f, 0.f, 0.f, 0.f};
#pragma unroll
    for (int r = 0; r < 4; ++r) { mrow[s2][r] = -3.4e38f; lrow[s2][r] = 0.f; }
  }

  const int rstage = tid >> 2;
  const int dstage = (tid & 3) * 16;
  const int ktmax = 2 * qt + 1;

  for (int kt = 0; kt <= ktmax; ++kt) {
    __syncthreads();
    {
      const size_t rowbase = ((size_t)bh * S_LEN + kt * 64 + rstage) * DH + dstage;
      const float* kp = Kg + rowbase;
      const float* vp = Vg + rowbase;
      float4 k0 = *(const float4*)kp;       float4 k1 = *(const float4*)(kp + 4);
      float4 k2 = *(const float4*)(kp + 8); float4 k3 = *(const float4*)(kp + 12);
      *(short8*)&Ks[rstage * 72 + dstage]     = pack8(k0, k1);
      *(short8*)&Ks[rstage * 72 + dstage + 8] = pack8(k2, k3);
      float4 v0 = *(const float4*)vp;       float4 v1 = *(const float4*)(vp + 4);
      float4 v2 = *(const float4*)(vp + 8); float4 v3 = *(const float4*)(vp + 12);
      float vv[16] = {v0.x, v0.y, v0.z, v0.w, v1.x, v1.y, v1.z, v1.w,
                      v2.x, v2.y, v2.z, v2.w, v3.x, v3.y, v3.z, v3.w};
#pragma unroll
      for (int i = 0; i < 16; ++i) Vt[(dstage + i) * 72 + rstage] = f2bf(vv[i]);
    }
    __syncthreads();

    float padv[4];
#pragma unroll
    for (int nt = 0; nt < 4; ++nt)
      padv[nt] = (maskg[b * S_LEN + kt * 64 + nt * 16 + c] != 0) ? 0.f : NEG_BIG;

    short8 kf[2][4];
#pragma unroll
    for (int ks = 0; ks < 2; ++ks)
#pragma unroll
      for (int nt = 0; nt < 4; ++nt)
        kf[ks][nt] = *(const short8*)&Ks[(nt * 16 + c) * 72 + ks * 32 + g * 8];

    bool act[2];
#pragma unroll
    for (int s2 = 0; s2 < 2; ++s2)
      act[s2] = (kt * 64) <= (qt * 128 + w * 32 + s2 * 16 + 15);

#pragma unroll
    for (int s2 = 0; s2 < 2; ++s2) {
      if (!act[s2]) continue;
      floatx4 sv[4];
#pragma unroll
      for (int nt = 0; nt < 4; ++nt) {
        floatx4 cc = (floatx4){0.f, 0.f, 0.f, 0.f};
        cc = MFMA32(qf[s2][0], kf[0][nt], cc);
        cc = MFMA32(qf[s2][1], kf[1][nt], cc);
        sv[nt] = cc;
      }
      const int qrow0 = qt * 128 + w * 32 + s2 * 16 + g * 4;
#pragma unroll
      for (int nt = 0; nt < 4; ++nt) {
        const int key = kt * 64 + nt * 16 + c;
#pragma unroll
        for (int r = 0; r < 4; ++r) {
          float s = sv[nt][r] * 0.125f + padv[nt];
          if (key > qrow0 + r) s = NEG_CAUSAL;
          sv[nt][r] = s;
        }
      }
#pragma unroll
      for (int r = 0; r < 4; ++r) {
        float mx = fmaxf(fmaxf(sv[0][r], sv[1][r]), fmaxf(sv[2][r], sv[3][r]));
        mx = fmaxf(mx, __shfl_xor(mx, 1));
        mx = fmaxf(mx, __shfl_xor(mx, 2));
        mx = fmaxf(mx, __shfl_xor(mx, 4));
        mx = fmaxf(mx, __shfl_xor(mx, 8));
        const float mold = mrow[s2][r];
        const float mnew = fmaxf(mold, mx);
        const float corr = fast_exp2((mold - mnew) * LOG2E);
        float ps = 0.f;
#pragma unroll
        for (int nt = 0; nt < 4; ++nt) {
          float p = fast_exp2((sv[nt][r] - mnew) * LOG2E);
          sv[nt][r] = p;
          ps += p;
        }
        ps += __shfl_xor(ps, 1);
        ps += __shfl_xor(ps, 2);
        ps += __shfl_xor(ps, 4);
        ps += __shfl_xor(ps, 8);
        lrow[s2][r] = lrow[s2][r] * corr + ps;
        mrow[s2][r] = mnew;
#pragma unroll
        for (int dt = 0; dt < 4; ++dt) acc[s2][dt][r] *= corr;
      }
#pragma unroll
      for (int nt = 0; nt < 4; ++nt)
#pragma unroll
        for (int r = 0; r < 4; ++r)
          Ps[w][(s2 * 16 + g * 4 + r) * 72 + nt * 16 + c] = f2bf(sv[nt][r]);
    }

#pragma unroll
    for (int ks = 0; ks < 2; ++ks) {
      short8 pf0 = {}, pf1 = {};
      if (act[0]) pf0 = *(const short8*)&Ps[w][c * 72 + ks * 32 + g * 8];
      if (act[1]) pf1 = *(const short8*)&Ps[w][(16 + c) * 72 + ks * 32 + g * 8];
#pragma unroll
      for (int dt = 0; dt < 4; ++dt) {
        short8 vfr = *(const short8*)&Vt[(dt * 16 + c) * 72 + ks * 32 + g * 8];
        if (act[0]) acc[0][dt] = MFMA32(pf0, vfr, acc[0][dt]);
        if (act[1]) acc[1][dt] = MFMA32(pf1, vfr, acc[1][dt]);
      }
    }
  }

#pragma unroll
  for (int s2 = 0; s2 < 2; ++s2) {
    float rl[4];
#pragma unroll
    for (int r = 0; r < 4; ++r) rl[r] = 1.f / lrow[s2][r];
    const size_t obase = ((size_t)bh * S_LEN + qt * 128 + w * 32 + s2 * 16 + g * 4) * DH + c;
#pragma unroll
    for (int dt = 0; dt < 4; ++dt)
#pragma unroll
      for (int r = 0; r < 4; ++r)
        Og[obase + (size_t)r * DH + dt * 16] = acc[s2][dt][r] * rl[r];
  }
}

// Rows q < f_b (f_b = first unpadded key of batch b) collapse in the fp32
// reference to a UNIFORM average over {k<=q} U {k>q, mask=1}. Overwrite them.
__global__ void fixup(const float* __restrict__ Vg, const int* __restrict__ maskg,
                      float* __restrict__ Og)
{
  const int bh = blockIdx.x;
  const int b  = bh & (NBATCH - 1);
  const int tid = (int)threadIdx.x;
  __shared__ int sFirst;
  __shared__ float sRed[16][64];
  __shared__ int sCnt[16];
  if (tid == 0) sFirst = S_LEN;
  __syncthreads();
  for (int k = tid; k < S_LEN; k += 1024)
    if (maskg[b * S_LEN + k] != 0) atomicMin(&sFirst, k);
  __syncthreads();
  const int f = sFirst;
  if (f == 0) return;

  const int d = tid & 63, kg = tid >> 6;   // kg in [0,16)
  float a = 0.f; int cnt = 0;
  for (int k = kg; k < S_LEN; k += 16) {
    if (maskg[b * S_LEN + k] != 0) { a += Vg[((size_t)bh * S_LEN + k) * DH + d]; cnt++; }
  }
  sRed[kg][d] = a;
  if (d == 0) sCnt[kg] = cnt;
  __syncthreads();
  if (tid < 64) {
    float ms = 0.f; int n = 0;
#pragma unroll
    for (int i = 0; i < 16; ++i) { ms += sRed[i][tid]; n += sCnt[i]; }
    float pre = 0.f;
    for (int q = 0; q < f; ++q) {
      pre += Vg[((size_t)bh * S_LEN + q) * DH + tid];
      Og[((size_t)bh * S_LEN + q) * DH + tid] = (pre + ms) / (float)(q + 1 + n);
    }
  }
}

extern "C" void kernel_launch(void* const* d_in, const int* in_sizes, int n_in,
                              void* d_out, int out_size, void* d_ws, size_t ws_size,
                              hipStream_t stream) {
  const float* Q = (const float*)d_in[0];
  const float* K = (const float*)d_in[1];
  const float* V = (const float*)d_in[2];
  const int* mask = (const int*)d_in[3];
  float* O = (float*)d_out;

  const size_t KF_BYTES = (size_t)64 * S_LEN * DH * 2;   // 16 MiB
  if (ws_size >= 2 * KF_BYTES) {
    short8* Kf = (short8*)d_ws;
    short8* Vf = (short8*)((char*)d_ws + KF_BYTES);
    prep_k<<<dim3(4096), dim3(256), 0, stream>>>(K, Kf);
    prep_v<<<dim3(4096), dim3(256), 0, stream>>>(V, Vf);
    flash_fwd2<<<dim3(64, 16), dim3(256), 0, stream>>>(Q, mask, Kf, Vf, O);
  } else {
    flash_fwd_lds<<<dim3(16, 64), dim3(256), 0, stream>>>(Q, K, V, mask, O);
  }
  fixup<<<dim3(64), dim3(1024), 0, stream>>>(V, mask, O);
}

// Round 4
// 222.000 us; speedup vs baseline: 2.6524x; 1.1827x over previous
//
#include <hip/hip_runtime.h>
#include <hip/hip_bf16.h>

#define S_LEN 2048
#define DH 64
#define NBATCH 4
#define LOG2E 1.44269504088896f
#define SCL2E 0.18033688011112042f      /* 0.125 * log2(e) */
#define PADC  (-1.44269504088896e10f)   /* -1e10 * log2(e): exp2 -> exactly 0 */
#define NEG_BIG -1e10f
#define NEG_CAUSAL -3.0e38f

typedef __attribute__((ext_vector_type(8))) short short8;
typedef __attribute__((ext_vector_type(4))) float floatx4;
typedef __attribute__((ext_vector_type(4))) unsigned uintx4;

__device__ inline float fast_exp2(float x) {
#if __has_builtin(__builtin_amdgcn_exp2f)
  return __builtin_amdgcn_exp2f(x);
#else
  return exp2f(x);
#endif
}

// fp32 -> bf16 round-to-nearest-even (finite inputs only)
__device__ inline short f2bf(float x) {
  union { float f; unsigned u; } v; v.f = x;
  unsigned r = v.u + 0x7fffu + ((v.u >> 16) & 1u);
  return (short)(r >> 16);
}

__device__ inline short8 pack8(float4 a, float4 b) {
  short8 r;
  r[0] = f2bf(a.x); r[1] = f2bf(a.y); r[2] = f2bf(a.z); r[3] = f2bf(a.w);
  r[4] = f2bf(b.x); r[5] = f2bf(b.y); r[6] = f2bf(b.z); r[7] = f2bf(b.w);
  return r;
}

// one uint = two bf16: low = lo.hi16, high = hi.hi16  (v_perm_b32)
__device__ inline unsigned packhi(unsigned hi, unsigned lo) {
#if __has_builtin(__builtin_amdgcn_perm)
  return __builtin_amdgcn_perm(hi, lo, 0x07060302u);
#else
  return (hi & 0xFFFF0000u) | (lo >> 16);
#endif
}

#define MFMA32(a, b, c) __builtin_amdgcn_mfma_f32_16x16x32_bf16(a, b, c, 0, 0, 0)

// ---------------- fused pre-pass: K and V -> fragment-linear bf16 -----------
// blocks [0,4096): K chunks. chunk idx = ((bh*32+kt)*8 + ks*4+nt)*64 + lane;
//   lane(c,g) holds K[bh][kt*64+nt*16+c][ks*32+g*8 .. +7]
// blocks [4096,8192): V chunks (k-permuted B-frags).
//   chunk idx = ((bh*32+kt)*8 + nt2*4+dt)*64 + lane; slot (g,j) -> key
//   kappa = kt*64 + nt2*32 + (j>=4)*16 + g*4 + (j&3); slot j holds V[kappa][dt*16+c]
__global__ void prep_kv(const float* __restrict__ Kg, const float* __restrict__ Vg,
                        short8* __restrict__ Kf, short8* __restrict__ Vf) {
  const int gid = (int)blockIdx.x;
  if (gid < 4096) {
    const int idx = gid * 256 + (int)threadIdx.x;
    const int lane = idx & 63;
    const int t = idx >> 6;
    const int nt = t & 3, ks = (t >> 2) & 1;
    const int kt = (t >> 3) & 31;
    const int bh = t >> 8;
    const int c = lane & 15, g = lane >> 4;
    const float* src = Kg + ((size_t)bh * S_LEN + kt * 64 + nt * 16 + c) * DH + ks * 32 + g * 8;
    float4 a = *(const float4*)src;
    float4 b = *(const float4*)(src + 4);
    Kf[idx] = pack8(a, b);
  } else {
    const int idx = (gid - 4096) * 256 + (int)threadIdx.x;
    const int lane = idx & 63;
    const int t = idx >> 6;
    const int dt = t & 3, nt2 = (t >> 2) & 1;
    const int kt = (t >> 3) & 31;
    const int bh = t >> 8;
    const int c = lane & 15, g = lane >> 4;
    const int key0 = kt * 64 + nt2 * 32 + g * 4;
    const float* src = Vg + ((size_t)bh * S_LEN + key0) * DH + dt * 16 + c;
    short8 r;
#pragma unroll
    for (int j = 0; j < 4; ++j) r[j] = f2bf(src[(size_t)j * DH]);
#pragma unroll
    for (int j = 0; j < 4; ++j) r[4 + j] = f2bf(src[(size_t)(16 + j) * DH]);
    Vf[idx] = r;
  }
}

// ---------------- main flash kernel: no LDS, no barriers --------------------
// grid = (64 bh, 16 qt'), qt = 15 - qt' (longest blocks dispatch first)
__global__ __launch_bounds__(256, 2) void flash_fwd2(
    const float* __restrict__ Qg, const int* __restrict__ maskg,
    const short8* __restrict__ KfB, const short8* __restrict__ VfB,
    float* __restrict__ Og)
{
  const int bh = blockIdx.x;
  const int qt = 15 - (int)blockIdx.y;
  const int b  = bh & (NBATCH - 1);
  const int tid = (int)threadIdx.x;
  const int w = tid >> 6, lane = tid & 63;
  const int c = lane & 15, g = lane >> 4;
  const int qbase = qt * 128 + w * 32;

  const short8 ones = {0x3F80, 0x3F80, 0x3F80, 0x3F80, 0x3F80, 0x3F80, 0x3F80, 0x3F80};

  // Q as B-fragments: lane(c,g) holds Q[q=qbase+s2*16+c][d=ks*32+g*8..+7]
  short8 qf[2][2];
#pragma unroll
  for (int s2 = 0; s2 < 2; ++s2) {
    const float* qp = Qg + ((size_t)bh * S_LEN + qbase + s2 * 16 + c) * DH + g * 8;
#pragma unroll
    for (int ks = 0; ks < 2; ++ks) {
      float4 a  = *(const float4*)(qp + ks * 32);
      float4 b4 = *(const float4*)(qp + ks * 32 + 4);
      qf[s2][ks] = pack8(a, b4);
    }
  }

  floatx4 acc[2][4];
  floatx4 acc_l[2];
#pragma unroll
  for (int s2 = 0; s2 < 2; ++s2) {
    acc_l[s2] = (floatx4){0.f, 0.f, 0.f, 0.f};
#pragma unroll
    for (int dt = 0; dt < 4; ++dt) acc[s2][dt] = (floatx4){0.f, 0.f, 0.f, 0.f};
  }

  const int ktmax = 2 * qt + 1;
  for (int kt = 0; kt <= ktmax; ++kt) {
    // K fragments (16B coalesced, L1/L2/L3-cached, shared by all 4 waves)
    const short8* kfp = KfB + ((size_t)(bh * 32 + kt) * 8) * 64 + lane;
    short8 kf[2][4];
#pragma unroll
    for (int ks = 0; ks < 2; ++ks)
#pragma unroll
      for (int nt = 0; nt < 4; ++nt) kf[ks][nt] = kfp[(ks * 4 + nt) * 64];

    // V fragments (16B coalesced, pre-permuted)
    const short8* vfp = VfB + ((size_t)(bh * 32 + kt) * 8) * 64 + lane;
    short8 vf[2][4];
#pragma unroll
    for (int nt2 = 0; nt2 < 2; ++nt2)
#pragma unroll
      for (int dt = 0; dt < 4; ++dt) vf[nt2][dt] = vfp[(nt2 * 4 + dt) * 64];

    // padding add (pre-multiplied by log2e), per key = kt*64+nt*16+g*4+r
    floatx4 padv[4];
#pragma unroll
    for (int nt = 0; nt < 4; ++nt) {
      int4 mv = *(const int4*)&maskg[b * S_LEN + kt * 64 + nt * 16 + g * 4];
      padv[nt][0] = mv.x ? 0.f : PADC;
      padv[nt][1] = mv.y ? 0.f : PADC;
      padv[nt][2] = mv.z ? 0.f : PADC;
      padv[nt][3] = mv.w ? 0.f : PADC;
    }

#pragma unroll
    for (int s2 = 0; s2 < 2; ++s2) {
      if (kt * 64 > qbase + s2 * 16 + 15) continue;   // fully above diagonal
      // S^T = K . Q^T : lane(c,g) reg r holds S[key=kt*64+nt*16+g*4+r][q=c]
      floatx4 st[4];
#pragma unroll
      for (int nt = 0; nt < 4; ++nt) {
        floatx4 cc = (floatx4){0.f, 0.f, 0.f, 0.f};
        cc = MFMA32(kf[0][nt], qf[s2][0], cc);
        cc = MFMA32(kf[1][nt], qf[s2][1], cc);
        st[nt] = cc;
      }
      const int q = qbase + s2 * 16 + c;
      const bool causal = (kt * 64 + 63) > (qbase + s2 * 16);
      unsigned pu[4][4];
#pragma unroll
      for (int nt = 0; nt < 4; ++nt) {
#pragma unroll
        for (int r = 0; r < 4; ++r) {
          float arg = fmaf(st[nt][r], SCL2E, padv[nt][r]);
          if (causal) {
            const int key = kt * 64 + nt * 16 + g * 4 + r;
            arg = (key > q) ? NEG_CAUSAL : arg;
          }
          // round-half-up to bf16 happens in packhi (+0x8000 then take hi16)
          pu[nt][r] = __float_as_uint(fast_exp2(arg)) + 0x8000u;
        }
      }
      // A-frags: tile (2*nt2) -> slots 0..3, tile (2*nt2+1) -> slots 4..7
      short8 pP[2];
#pragma unroll
      for (int nt2 = 0; nt2 < 2; ++nt2) {
        uintx4 wv;
        wv[0] = packhi(pu[2 * nt2][1],     pu[2 * nt2][0]);
        wv[1] = packhi(pu[2 * nt2][3],     pu[2 * nt2][2]);
        wv[2] = packhi(pu[2 * nt2 + 1][1], pu[2 * nt2 + 1][0]);
        wv[3] = packhi(pu[2 * nt2 + 1][3], pu[2 * nt2 + 1][2]);
        pP[nt2] = __builtin_bit_cast(short8, wv);
      }
      // PV + row-sum of P (ones-column MFMA) — P never leaves registers
#pragma unroll
      for (int nt2 = 0; nt2 < 2; ++nt2) {
        acc_l[s2] = MFMA32(pP[nt2], ones, acc_l[s2]);
#pragma unroll
        for (int dt = 0; dt < 4; ++dt)
          acc[s2][dt] = MFMA32(pP[nt2], vf[nt2][dt], acc[s2][dt]);
      }
    }
  }

  // epilogue: acc_l rows match acc rows exactly (row = g*4+r) — no shuffles
#pragma unroll
  for (int s2 = 0; s2 < 2; ++s2) {
    float rr[4];
#pragma unroll
    for (int r = 0; r < 4; ++r) rr[r] = 1.f / acc_l[s2][r];  // inf rows: fixup overwrites
#pragma unroll
    for (int dt = 0; dt < 4; ++dt)
#pragma unroll
      for (int r = 0; r < 4; ++r)
        Og[((size_t)bh * S_LEN + qbase + s2 * 16 + g * 4 + r) * DH + dt * 16 + c] =
            acc[s2][dt][r] * rr[r];
  }
}

// ---------------- fallback (ws too small): round-1 kernel ------------------
__global__ __launch_bounds__(256, 2) void flash_fwd_lds(
    const float* __restrict__ Qg, const float* __restrict__ Kg,
    const float* __restrict__ Vg, const int* __restrict__ maskg,
    float* __restrict__ Og)
{
  const int qt  = blockIdx.x;
  const int bh  = blockIdx.y;
  const int b   = bh & (NBATCH - 1);
  const int tid = (int)threadIdx.x;
  const int w = tid >> 6, lane = tid & 63;
  const int g = lane >> 4, c = lane & 15;

  __shared__ __align__(16) short Ks[64 * 72];
  __shared__ __align__(16) short Vt[64 * 72];
  __shared__ __align__(16) short Ps[4][32 * 72];

  short8 qf[2][2];
#pragma unroll
  for (int s2 = 0; s2 < 2; ++s2) {
    const float* qp = Qg + ((size_t)bh * S_LEN + qt * 128 + w * 32 + s2 * 16 + c) * DH + g * 8;
#pragma unroll
    for (int ks = 0; ks < 2; ++ks) {
      float4 a  = *(const float4*)(qp + ks * 32);
      float4 bq = *(const float4*)(qp + ks * 32 + 4);
      qf[s2][ks] = pack8(a, bq);
    }
  }

  floatx4 acc[2][4];
  float mrow[2][4], lrow[2][4];
#pragma unroll
  for (int s2 = 0; s2 < 2; ++s2) {
#pragma unroll
    for (int i = 0; i < 4; ++i) acc[s2][i] = (floatx4){0.f, 0.f, 0.f, 0.f};
#pragma unroll
    for (int r = 0; r < 4; ++r) { mrow[s2][r] = -3.4e38f; lrow[s2][r] = 0.f; }
  }

  const int rstage = tid >> 2;
  const int dstage = (tid & 3) * 16;
  const int ktmax = 2 * qt + 1;

  for (int kt = 0; kt <= ktmax; ++kt) {
    __syncthreads();
    {
      const size_t rowbase = ((size_t)bh * S_LEN + kt * 64 + rstage) * DH + dstage;
      const float* kp = Kg + rowbase;
      const float* vp = Vg + rowbase;
      float4 k0 = *(const float4*)kp;       float4 k1 = *(const float4*)(kp + 4);
      float4 k2 = *(const float4*)(kp + 8); float4 k3 = *(const float4*)(kp + 12);
      *(short8*)&Ks[rstage * 72 + dstage]     = pack8(k0, k1);
      *(short8*)&Ks[rstage * 72 + dstage + 8] = pack8(k2, k3);
      float4 v0 = *(const float4*)vp;       float4 v1 = *(const float4*)(vp + 4);
      float4 v2 = *(const float4*)(vp + 8); float4 v3 = *(const float4*)(vp + 12);
      float vv[16] = {v0.x, v0.y, v0.z, v0.w, v1.x, v1.y, v1.z, v1.w,
                      v2.x, v2.y, v2.z, v2.w, v3.x, v3.y, v3.z, v3.w};
#pragma unroll
      for (int i = 0; i < 16; ++i) Vt[(dstage + i) * 72 + rstage] = f2bf(vv[i]);
    }
    __syncthreads();

    float padv[4];
#pragma unroll
    for (int nt = 0; nt < 4; ++nt)
      padv[nt] = (maskg[b * S_LEN + kt * 64 + nt * 16 + c] != 0) ? 0.f : NEG_BIG;

    short8 kf[2][4];
#pragma unroll
    for (int ks = 0; ks < 2; ++ks)
#pragma unroll
      for (int nt = 0; nt < 4; ++nt)
        kf[ks][nt] = *(const short8*)&Ks[(nt * 16 + c) * 72 + ks * 32 + g * 8];

    bool act[2];
#pragma unroll
    for (int s2 = 0; s2 < 2; ++s2)
      act[s2] = (kt * 64) <= (qt * 128 + w * 32 + s2 * 16 + 15);

#pragma unroll
    for (int s2 = 0; s2 < 2; ++s2) {
      if (!act[s2]) continue;
      floatx4 sv[4];
#pragma unroll
      for (int nt = 0; nt < 4; ++nt) {
        floatx4 cc = (floatx4){0.f, 0.f, 0.f, 0.f};
        cc = MFMA32(qf[s2][0], kf[0][nt], cc);
        cc = MFMA32(qf[s2][1], kf[1][nt], cc);
        sv[nt] = cc;
      }
      const int qrow0 = qt * 128 + w * 32 + s2 * 16 + g * 4;
#pragma unroll
      for (int nt = 0; nt < 4; ++nt) {
        const int key = kt * 64 + nt * 16 + c;
#pragma unroll
        for (int r = 0; r < 4; ++r) {
          float s = sv[nt][r] * 0.125f + padv[nt];
          if (key > qrow0 + r) s = NEG_CAUSAL;
          sv[nt][r] = s;
        }
      }
#pragma unroll
      for (int r = 0; r < 4; ++r) {
        float mx = fmaxf(fmaxf(sv[0][r], sv[1][r]), fmaxf(sv[2][r], sv[3][r]));
        mx = fmaxf(mx, __shfl_xor(mx, 1));
        mx = fmaxf(mx, __shfl_xor(mx, 2));
        mx = fmaxf(mx, __shfl_xor(mx, 4));
        mx = fmaxf(mx, __shfl_xor(mx, 8));
        const float mold = mrow[s2][r];
        const float mnew = fmaxf(mold, mx);
        const float corr = fast_exp2((mold - mnew) * LOG2E);
        float ps = 0.f;
#pragma unroll
        for (int nt = 0; nt < 4; ++nt) {
          float p = fast_exp2((sv[nt][r] - mnew) * LOG2E);
          sv[nt][r] = p;
          ps += p;
        }
        ps += __shfl_xor(ps, 1);
        ps += __shfl_xor(ps, 2);
        ps += __shfl_xor(ps, 4);
        ps += __shfl_xor(ps, 8);
        lrow[s2][r] = lrow[s2][r] * corr + ps;
        mrow[s2][r] = mnew;
#pragma unroll
        for (int dt = 0; dt < 4; ++dt) acc[s2][dt][r] *= corr;
      }
#pragma unroll
      for (int nt = 0; nt < 4; ++nt)
#pragma unroll
        for (int r = 0; r < 4; ++r)
          Ps[w][(s2 * 16 + g * 4 + r) * 72 + nt * 16 + c] = f2bf(sv[nt][r]);
    }

#pragma unroll
    for (int ks = 0; ks < 2; ++ks) {
      short8 pf0 = {}, pf1 = {};
      if (act[0]) pf0 = *(const short8*)&Ps[w][c * 72 + ks * 32 + g * 8];
      if (act[1]) pf1 = *(const short8*)&Ps[w][(16 + c) * 72 + ks * 32 + g * 8];
#pragma unroll
      for (int dt = 0; dt < 4; ++dt) {
        short8 vfr = *(const short8*)&Vt[(dt * 16 + c) * 72 + ks * 32 + g * 8];
        if (act[0]) acc[0][dt] = MFMA32(pf0, vfr, acc[0][dt]);
        if (act[1]) acc[1][dt] = MFMA32(pf1, vfr, acc[1][dt]);
      }
    }
  }

#pragma unroll
  for (int s2 = 0; s2 < 2; ++s2) {
    float rl[4];
#pragma unroll
    for (int r = 0; r < 4; ++r) rl[r] = 1.f / lrow[s2][r];
    const size_t obase = ((size_t)bh * S_LEN + qt * 128 + w * 32 + s2 * 16 + g * 4) * DH + c;
#pragma unroll
    for (int dt = 0; dt < 4; ++dt)
#pragma unroll
      for (int r = 0; r < 4; ++r)
        Og[obase + (size_t)r * DH + dt * 16] = acc[s2][dt][r] * rl[r];
  }
}

// Rows q < f_b (f_b = first unpadded key of batch b) collapse in the fp32
// reference to a UNIFORM average over {k<=q} U {k>q, mask=1}. Overwrite them.
// float4 sum: 64 k-groups x 16 d-quads -> 32-iteration chains.
__global__ void fixup(const float* __restrict__ Vg, const int* __restrict__ maskg,
                      float* __restrict__ Og)
{
  const int bh = blockIdx.x;
  const int b  = bh & (NBATCH - 1);
  const int tid = (int)threadIdx.x;
  __shared__ int sFirst;
  __shared__ float4 sRed[64][16];
  __shared__ int sCnt[64];
  if (tid == 0) sFirst = S_LEN;
  __syncthreads();
  for (int k = tid; k < S_LEN; k += 1024)
    if (maskg[b * S_LEN + k] != 0) atomicMin(&sFirst, k);
  __syncthreads();
  const int f = sFirst;
  if (f == 0) return;

  const int dq = tid & 15, kg = tid >> 4;   // 16 d-quads, 64 k-groups
  float4 a = {0.f, 0.f, 0.f, 0.f}; int cnt = 0;
  for (int k = kg; k < S_LEN; k += 64) {
    if (maskg[b * S_LEN + k] != 0) {
      float4 v = *(const float4*)&Vg[((size_t)bh * S_LEN + k) * DH + dq * 4];
      a.x += v.x; a.y += v.y; a.z += v.z; a.w += v.w; cnt++;
    }
  }
  sRed[kg][dq] = a;
  if (dq == 0) sCnt[kg] = cnt;
  __syncthreads();
  if (tid < 64) {
    const int q4 = tid >> 2, e = tid & 3;   // d = tid
    float ms = 0.f; int n = 0;
#pragma unroll 4
    for (int i = 0; i < 64; ++i) {
      const float* p4 = (const float*)&sRed[i][q4];
      ms += p4[e];
      n += sCnt[i];
    }
    float pre = 0.f;
    for (int q = 0; q < f; ++q) {
      pre += Vg[((size_t)bh * S_LEN + q) * DH + tid];
      Og[((size_t)bh * S_LEN + q) * DH + tid] = (pre + ms) / (float)(q + 1 + n);
    }
  }
}

extern "C" void kernel_launch(void* const* d_in, const int* in_sizes, int n_in,
                              void* d_out, int out_size, void* d_ws, size_t ws_size,
                              hipStream_t stream) {
  const float* Q = (const float*)d_in[0];
  const float* K = (const float*)d_in[1];
  const float* V = (const float*)d_in[2];
  const int* mask = (const int*)d_in[3];
  float* O = (float*)d_out;

  const size_t KF_BYTES = (size_t)64 * S_LEN * DH * 2;   // 16 MiB
  if (ws_size >= 2 * KF_BYTES) {
    short8* Kf = (short8*)d_ws;
    short8* Vf = (short8*)((char*)d_ws + KF_BYTES);
    prep_kv<<<dim3(8192), dim3(256), 0, stream>>>(K, V, Kf, Vf);
    flash_fwd2<<<dim3(64, 16), dim3(256), 0, stream>>>(Q, mask, Kf, Vf, O);
  } else {
    flash_fwd_lds<<<dim3(16, 64), dim3(256), 0, stream>>>(Q, K, V, mask, O);
  }
  fixup<<<dim3(64), dim3(1024), 0, stream>>>(V, mask, O);
}